// Round 1
// baseline (704.958 us; speedup 1.0000x reference)
//
#include <hip/hip_runtime.h>

#define N_NODES 100000
#define F_IN 128
#define F_OUT 64

// ---------------------------------------------------------------------------
// Kernel 1: support = X (N,128) @ W (128,64), fp32 vector ALU.
// W staged fully in LDS (32 KB). One wave per row; lane = output column.
// ---------------------------------------------------------------------------
__global__ void __launch_bounds__(256) gnn_gemm_kernel(
    const float* __restrict__ X, const float* __restrict__ W,
    float* __restrict__ support, int n_rows) {
    __shared__ float Wlds[F_IN * F_OUT];  // 32 KB
    for (int i = threadIdx.x; i < F_IN * F_OUT; i += blockDim.x)
        Wlds[i] = W[i];
    __syncthreads();

    const int lane    = threadIdx.x & 63;
    const int wave    = (blockIdx.x * blockDim.x + threadIdx.x) >> 6;
    const int n_waves = (gridDim.x * blockDim.x) >> 6;

    for (int row = wave; row < n_rows; row += n_waves) {
        const float4* xr = reinterpret_cast<const float4*>(X + (size_t)row * F_IN);
        float acc = 0.f;
#pragma unroll
        for (int k4 = 0; k4 < F_IN / 4; ++k4) {
            float4 x = xr[k4];  // wave-uniform address -> scalar/broadcast load
            acc = fmaf(x.x, Wlds[(k4 * 4 + 0) * F_OUT + lane], acc);
            acc = fmaf(x.y, Wlds[(k4 * 4 + 1) * F_OUT + lane], acc);
            acc = fmaf(x.z, Wlds[(k4 * 4 + 2) * F_OUT + lane], acc);
            acc = fmaf(x.w, Wlds[(k4 * 4 + 3) * F_OUT + lane], acc);
        }
        support[(size_t)row * F_OUT + lane] = acc;
    }
}

// ---------------------------------------------------------------------------
// Kernel 2: out[dst] += support[src] * ew  (atomic scatter-add).
// One wave per edge; lane = feature index. Edge metadata is wave-uniform.
// ---------------------------------------------------------------------------
__global__ void __launch_bounds__(256) gnn_scatter_kernel(
    const float* __restrict__ support, const int* __restrict__ edge_index,
    const float* __restrict__ edge_weight, float* __restrict__ out, int n_edges) {
    const int lane    = threadIdx.x & 63;
    const int wave    = (blockIdx.x * blockDim.x + threadIdx.x) >> 6;
    const int n_waves = (gridDim.x * blockDim.x) >> 6;

    for (int e = wave; e < n_edges; e += n_waves) {
        const int   dst = edge_index[e];            // row 0: dst
        const int   src = edge_index[n_edges + e];  // row 1: src
        const float w   = edge_weight[e];
        const float v   = support[(size_t)src * F_OUT + lane] * w;
        atomicAdd(&out[(size_t)dst * F_OUT + lane], v);
    }
}

// ---------------------------------------------------------------------------
// Kernel 3: in-place ReLU, float4-vectorized.
// ---------------------------------------------------------------------------
__global__ void __launch_bounds__(256) gnn_relu_kernel(float* __restrict__ out, int n4) {
    int i            = blockIdx.x * blockDim.x + threadIdx.x;
    const int stride = gridDim.x * blockDim.x;
    float4* p = reinterpret_cast<float4*>(out);
    for (; i < n4; i += stride) {
        float4 v = p[i];
        v.x = fmaxf(v.x, 0.f);
        v.y = fmaxf(v.y, 0.f);
        v.z = fmaxf(v.z, 0.f);
        v.w = fmaxf(v.w, 0.f);
        p[i] = v;
    }
}

extern "C" void kernel_launch(void* const* d_in, const int* in_sizes, int n_in,
                              void* d_out, int out_size, void* d_ws, size_t ws_size,
                              hipStream_t stream) {
    const float* X  = (const float*)d_in[0];   // [100000,128] fp32
    const float* W  = (const float*)d_in[1];   // [128,64] fp32
    const int*   EI = (const int*)d_in[2];     // [2,E] int
    const float* EW = (const float*)d_in[3];   // [E] fp32
    float*       out     = (float*)d_out;      // [100000,64] fp32
    float*       support = (float*)d_ws;       // [100000,64] fp32 scratch

    const int n_edges = in_sizes[2] / 2;
    const int n_rows  = in_sizes[0] / F_IN;

    // out is poisoned to 0xAA each timed call — zero it (graph-capture-safe).
    hipMemsetAsync(d_out, 0, (size_t)out_size * sizeof(float), stream);

    gnn_gemm_kernel<<<1024, 256, 0, stream>>>(X, W, support, n_rows);
    gnn_scatter_kernel<<<2048, 256, 0, stream>>>(support, EI, EW, out, n_edges);
    gnn_relu_kernel<<<2048, 256, 0, stream>>>(out, out_size / 4);
}

// Round 2
// 457.715 us; speedup vs baseline: 1.5402x; 1.5402x over previous
//
#include <hip/hip_runtime.h>
#include <hip/hip_bf16.h>

#define F_IN 128
#define F_OUT 64

__device__ __forceinline__ float f4c(const float4& v, int j) {
    switch (j) { case 0: return v.x; case 1: return v.y; case 2: return v.z; default: return v.w; }
}

// ---------------------------------------------------------------------------
// support(bf16) = X (N,128) @ W (128,64). 8 rows per wave: each ds_read of W
// feeds 8 FMAs (LDS instr count 8x lower than 1-row version).
// Requires n_rows % 32 == 0 (100000 = 3125 blocks * 4 waves * 8 rows, exact).
// ---------------------------------------------------------------------------
__global__ void __launch_bounds__(256) gnn_gemm_kernel(
    const float* __restrict__ X, const float* __restrict__ W,
    __hip_bfloat16* __restrict__ support, int n_rows) {
    __shared__ float Wlds[F_IN * F_OUT];  // 32 KB
    for (int i = threadIdx.x; i < F_IN * F_OUT; i += 256) Wlds[i] = W[i];
    __syncthreads();

    const int lane = threadIdx.x & 63;
    const int wid  = threadIdx.x >> 6;
    const int row0 = (blockIdx.x * 4 + wid) * 8;
    if (row0 + 8 > n_rows) return;

    const float4* x0 = reinterpret_cast<const float4*>(X + (size_t)row0 * F_IN);
    float acc[8] = {0.f, 0.f, 0.f, 0.f, 0.f, 0.f, 0.f, 0.f};

    for (int k4 = 0; k4 < F_IN / 4; ++k4) {
        float4 xr[8];
#pragma unroll
        for (int r = 0; r < 8; ++r) xr[r] = x0[r * (F_IN / 4) + k4];
#pragma unroll
        for (int j = 0; j < 4; ++j) {
            const float w = Wlds[(k4 * 4 + j) * F_OUT + lane];
#pragma unroll
            for (int r = 0; r < 8; ++r) acc[r] = fmaf(f4c(xr[r], j), w, acc[r]);
        }
    }
#pragma unroll
    for (int r = 0; r < 8; ++r)
        support[(size_t)(row0 + r) * F_OUT + lane] = __float2bfloat16(acc[r]);
}

// ---------------------------------------------------------------------------
// CSR build: histogram -> exclusive scan (3 kernels) -> fill.
// ---------------------------------------------------------------------------
__global__ void __launch_bounds__(256) gnn_hist_kernel(
    const int* __restrict__ dst, int* __restrict__ counts, int n_edges) {
    int i = blockIdx.x * 256 + threadIdx.x;
    const int stride = gridDim.x * 256;
    for (; i < n_edges; i += stride) atomicAdd(&counts[dst[i]], 1);
}

__global__ void __launch_bounds__(256) gnn_scanA_kernel(
    const int* __restrict__ counts, int* __restrict__ cursor,
    int* __restrict__ partials, int n) {
    __shared__ int s[256];
    const int t = threadIdx.x;
    const int i = blockIdx.x * 256 + t;
    const int v = (i < n) ? counts[i] : 0;
    s[t] = v;
    __syncthreads();
    for (int off = 1; off < 256; off <<= 1) {
        int x = (t >= off) ? s[t - off] : 0;
        __syncthreads();
        s[t] += x;
        __syncthreads();
    }
    if (i < n) cursor[i] = s[t] - v;        // block-local exclusive
    if (t == 255) partials[blockIdx.x] = s[255];
}

__global__ void __launch_bounds__(512) gnn_scanB_kernel(int* __restrict__ partials, int nb) {
    __shared__ int s[512];
    const int t = threadIdx.x;
    const int v = (t < nb) ? partials[t] : 0;
    s[t] = v;
    __syncthreads();
    for (int off = 1; off < 512; off <<= 1) {
        int x = (t >= off) ? s[t - off] : 0;
        __syncthreads();
        s[t] += x;
        __syncthreads();
    }
    if (t < nb) partials[t] = s[t] - v;     // exclusive block offsets
}

__global__ void __launch_bounds__(256) gnn_scanC_kernel(
    int* __restrict__ cursor, const int* __restrict__ partials, int n) {
    const int i = blockIdx.x * 256 + threadIdx.x;
    if (i < n) cursor[i] += partials[blockIdx.x];
}

// fill: cursor starts as exclusive offsets; after fill, cursor[i] == end_i.
__global__ void __launch_bounds__(256) gnn_fill_kernel(
    const int* __restrict__ ei, const float* __restrict__ ew,
    int* __restrict__ cursor, int2* __restrict__ elist, int n_edges) {
    int i = blockIdx.x * 256 + threadIdx.x;
    const int stride = gridDim.x * 256;
    for (; i < n_edges; i += stride) {
        const int d = ei[i];
        const int s = ei[n_edges + i];
        const float w = ew[i];
        const int pos = atomicAdd(&cursor[d], 1);
        elist[pos] = make_int2(s, __float_as_int(w));
    }
}

// ---------------------------------------------------------------------------
// Pull: one wave per node, lane = feature. start = ends[node-1], end = ends[node]
// (bins are contiguous so end_{i-1} == start_i). Fused ReLU, plain writes.
// ---------------------------------------------------------------------------
__global__ void __launch_bounds__(256) gnn_pull_kernel(
    const __hip_bfloat16* __restrict__ support, const int2* __restrict__ elist,
    const int* __restrict__ ends, float* __restrict__ out, int n_nodes) {
    const int lane = threadIdx.x & 63;
    const int node = blockIdx.x * 4 + (threadIdx.x >> 6);
    if (node >= n_nodes) return;

    const int start = (node == 0) ? 0 : ends[node - 1];
    const int end   = ends[node];

    float acc = 0.f;
    int e = start;
    for (; e + 2 <= end; e += 2) {           // 2-wide: two gathers in flight
        const int2 e0 = elist[e];
        const int2 e1 = elist[e + 1];
        const float g0 = __bfloat162float(support[(size_t)e0.x * F_OUT + lane]);
        const float g1 = __bfloat162float(support[(size_t)e1.x * F_OUT + lane]);
        acc = fmaf(__int_as_float(e0.y), g0, acc);
        acc = fmaf(__int_as_float(e1.y), g1, acc);
    }
    if (e < end) {
        const int2 e0 = elist[e];
        acc = fmaf(__int_as_float(e0.y),
                   __bfloat162float(support[(size_t)e0.x * F_OUT + lane]), acc);
    }
    out[(size_t)node * F_OUT + lane] = fmaxf(acc, 0.f);
}

extern "C" void kernel_launch(void* const* d_in, const int* in_sizes, int n_in,
                              void* d_out, int out_size, void* d_ws, size_t ws_size,
                              hipStream_t stream) {
    const float* X  = (const float*)d_in[0];   // [N,128] fp32
    const float* W  = (const float*)d_in[1];   // [128,64] fp32
    const int*   EI = (const int*)d_in[2];     // [2,E] int32
    const float* EW = (const float*)d_in[3];   // [E] fp32
    float*       out = (float*)d_out;          // [N,64] fp32

    const int n_edges = in_sizes[2] / 2;       // 1,600,000
    const int n_rows  = in_sizes[0] / F_IN;    // 100,000
    const int n_nodes = out_size / F_OUT;      // 100,000

    // Workspace layout (~26.4 MB total)
    char* ws = (char*)d_ws;
    __hip_bfloat16* support = (__hip_bfloat16*)ws;                        // 12.8 MB
    size_t off = (size_t)n_rows * F_OUT * sizeof(__hip_bfloat16);
    int2* elist = (int2*)(ws + off);  off += (size_t)n_edges * sizeof(int2);  // 12.8 MB
    int* counts = (int*)(ws + off);   off += (size_t)n_nodes * sizeof(int);   // 400 KB
    int* cursor = (int*)(ws + off);   off += (size_t)n_nodes * sizeof(int);   // 400 KB
    int* partials = (int*)(ws + off);                                         // ~1.6 KB

    const int nb = (n_nodes + 255) / 256;      // 391 (<= 512 for scanB)

    hipMemsetAsync(counts, 0, (size_t)n_nodes * sizeof(int), stream);

    gnn_gemm_kernel<<<n_rows / 32, 256, 0, stream>>>(X, W, support, n_rows);
    gnn_hist_kernel<<<2048, 256, 0, stream>>>(EI, counts, n_edges);
    gnn_scanA_kernel<<<nb, 256, 0, stream>>>(counts, cursor, partials, n_nodes);
    gnn_scanB_kernel<<<1, 512, 0, stream>>>(partials, nb);
    gnn_scanC_kernel<<<nb, 256, 0, stream>>>(cursor, partials, n_nodes);
    gnn_fill_kernel<<<2048, 256, 0, stream>>>(EI, EW, cursor, elist, n_edges);
    gnn_pull_kernel<<<(n_nodes + 3) / 4, 256, 0, stream>>>(support, elist, cursor, out, n_nodes);
}